// Round 5
// baseline (172.958 us; speedup 1.0000x reference)
//
#include <hip/hip_runtime.h>

typedef __attribute__((ext_vector_type(8))) short bf16x8;
typedef __attribute__((ext_vector_type(4))) float f32x4;

#define NPTS   40000
#define MOUT   40000
#define EDG    500000
#define FIN    32
#define COUT   64
#define KP     15
#define KFDIM  (KP * FIN)          // 480
#define TM     16                  // output points per block
#define ASTRIDE 488                // bf16 elems; 976B row -> 2-way LDS aliasing (free)
#define EXTENT 0.6f

__device__ __forceinline__ short f2bf(float x) {
    union { float f; unsigned u; } v; v.f = x;
    unsigned r = (v.u + 0x7fffu + ((v.u >> 16) & 1u)) >> 16;
    return (short)r;
}

// (256,6): VGPR cap 85 — safely above natural ~50-64 demand (R3 lesson: a cap
// below natural demand causes catastrophic scratch spills, WRITE_SIZE 10->162MB).
// 6 blocks/CU x 15.9KB LDS = 95KB < 160KB -> occupancy now VGPR/bound-limited at
// 24 waves/CU (was 16).
__global__ __launch_bounds__(256, 6) void kpconv_fused(
    const float* __restrict__ points,
    const float* __restrict__ features,
    const float* __restrict__ output_points,
    const int*   __restrict__ nbr_idx,
    const int*   __restrict__ seg_ids,
    const float* __restrict__ k_points,
    const float* __restrict__ k_values,
    float*       __restrict__ out)
{
    __shared__ __align__(16) unsigned short agg[TM * ASTRIDE];  // 15616 B
    __shared__ int seg_start[TM + 1];

    const int tid = threadIdx.x;
    const int m0  = blockIdx.x * TM;

    // ---- segment range binary search (segment_ids is sorted) ----
    if (tid <= TM) {
        const int target = m0 + tid;
        int lo = 0, hi = EDG;
        while (lo < hi) {
            int mid = (lo + hi) >> 1;
            if (seg_ids[mid] < target) lo = mid + 1; else hi = mid;
        }
        seg_start[tid] = lo;
    }
    __syncthreads();

    const int wave = tid >> 6;
    const int lane = tid & 63;
    const int quad = lane >> 4;      // 0..3 (= edge slot in phase 1)
    const int l16  = lane & 15;      // 0..15 (= kernel point in phase 1, k=15 idle)
    const int hi5  = lane >> 5;      // 0 or 1
    const int f    = lane & 31;      // feature channel owned by this lane

    // per-lane kernel point (lane's k = l16; k==15 lanes produce w=0)
    const int myk = l16 < KP ? l16 : (KP - 1);
    const float kpx = k_points[myk * 3 + 0];
    const float kpy = k_points[myk * 3 + 1];
    const float kpz = k_points[myk * 3 + 2];
    const float inv_ext = 1.f / EXTENT;

    // ---- Phase 1: 4 edges per wave-step; lane = 16*edge_slot + k ----
    for (int l = wave * 4; l < wave * 4 + 4; ++l) {
        float acc[8];
        #pragma unroll
        for (int j = 0; j < 8; ++j) acc[j] = 0.f;

        const int m  = m0 + l;
        const float ox = output_points[m * 3 + 0];
        const float oy = output_points[m * 3 + 1];
        const float oz = output_points[m * 3 + 2];
        const int e0 = seg_start[l], e1 = seg_start[l + 1];

        for (int e = e0; e < e1; e += 4) {
            const int last = e1 - 1;
            const int c1 = e + 1 < e1 ? e + 1 : last;
            const int c2 = e + 2 < e1 ? e + 2 : last;
            const int c3 = e + 3 < e1 ? e + 3 : last;
            const int nb0 = nbr_idx[e];
            const int nb1 = nbr_idx[c1];
            const int nb2 = nbr_idx[c2];
            const int nb3 = nbr_idx[c3];

            // this lane's own edge for the weight computation
            const int nb_a  = (quad & 1) ? nb1 : nb0;
            const int nb_b  = (quad & 1) ? nb3 : nb2;
            const int nb_own = (quad & 2) ? nb_b : nb_a;
            const float* pp = points + nb_own * 3;
            const float rx = pp[0] - ox;
            const float ry = pp[1] - oy;
            const float rz = pp[2] - oz;
            const float dx = rx - kpx, dy = ry - kpy, dz = rz - kpz;
            const float d2 = dx * dx + dy * dy + dz * dz;
            float w = 1.f - sqrtf(d2) * inv_ext;
            w = w > 0.f ? w : 0.f;
            // kill k==15 lanes and tail edge slots (duplicated clamped edges)
            const int nvalid = e1 - e;
            if (l16 >= KP || quad >= nvalid) w = 0.f;

            // features for all 4 edges at this lane's channel
            const float fv0 = features[nb0 * FIN + f];
            const float fv1 = features[nb1 * FIN + f];
            const float fv2 = features[nb2 * FIN + f];
            const float fv3 = features[nb3 * FIN + f];

            #pragma unroll
            for (int j = 0; j < 8; ++j) {
                const int kj = 2 * j + hi5;          // 0..15; k=15 sources hold w=0
                acc[j] += __shfl(w, kj)      * fv0;
                acc[j] += __shfl(w, 16 + kj) * fv1;
                acc[j] += __shfl(w, 32 + kj) * fv2;
                acc[j] += __shfl(w, 48 + kj) * fv3;
            }
        }

        #pragma unroll
        for (int j = 0; j < 8; ++j) {
            const int idx = lane + 64 * j;          // = k*32 + f
            if (idx < KFDIM) agg[l * ASTRIDE + idx] = (unsigned short)f2bf(acc[j]);
        }
    }

    __syncthreads();

    // ---- Phase 2: C[16x16] per wave via 15 MFMAs over K=480 ----
    // B fragments loaded per-step (NOT prefetched across phase 1 — holding
    // bfr[15] = 30 VGPRs across the barrier is what capped occupancy at 4
    // blocks/CU in R2/R4). Each step's 8 loads: 16 consecutive bcol lanes
    // x 4B = coalesced 64B lines, k_values is L2-resident.
    const int bcol = wave * 16 + l16;
    const float* wbase = k_values + (quad * 8) * COUT + bcol;

    f32x4 c = {0.f, 0.f, 0.f, 0.f};
    #pragma unroll
    for (int s = 0; s < 15; ++s) {
        bf16x8 b;
        #pragma unroll
        for (int j = 0; j < 8; ++j)
            b[j] = f2bf(wbase[(32 * s + j) * COUT]);
        const bf16x8 a = *(const bf16x8*)&agg[l16 * ASTRIDE + 32 * s + quad * 8];
        c = __builtin_amdgcn_mfma_f32_16x16x32_bf16(a, b, c, 0, 0, 0);
    }

    // C/D layout: col = lane&15, row = quad*4 + reg
    #pragma unroll
    for (int r = 0; r < 4; ++r) {
        const int row = quad * 4 + r;
        out[(m0 + row) * COUT + wave * 16 + l16] = c[r];
    }
}

extern "C" void kernel_launch(void* const* d_in, const int* in_sizes, int n_in,
                              void* d_out, int out_size, void* d_ws, size_t ws_size,
                              hipStream_t stream) {
    const float* points        = (const float*)d_in[0];
    const float* features      = (const float*)d_in[1];
    const float* output_points = (const float*)d_in[2];
    const int*   nbr_idx       = (const int*)d_in[3];
    const int*   seg_ids       = (const int*)d_in[4];
    const float* k_points      = (const float*)d_in[5];
    const float* k_values      = (const float*)d_in[6];
    float* out = (float*)d_out;

    kpconv_fused<<<MOUT / TM, 256, 0, stream>>>(
        points, features, output_points, nbr_idx, seg_ids,
        k_points, k_values, out);
}

// Round 6
// 157.810 us; speedup vs baseline: 1.0960x; 1.0960x over previous
//
#include <hip/hip_runtime.h>

typedef __attribute__((ext_vector_type(8))) short bf16x8;
typedef __attribute__((ext_vector_type(4))) float f32x4;

#define NPTS   40000
#define MOUT   40000
#define EDG    500000
#define FIN    32
#define COUT   64
#define KP     15
#define KFDIM  (KP * FIN)          // 480
#define TM     16                  // output points per block (kernel A)
#define ASTRIDE 488                // fused-fallback LDS stride
#define EXTENT 0.6f

__device__ __forceinline__ short f2bf(float x) {
    union { float f; unsigned u; } v; v.f = x;
    unsigned r = (v.u + 0x7fffu + ((v.u >> 16) & 1u)) >> 16;
    return (short)r;
}

// ============================================================================
// Kernel A: aggregation only (R4's proven phase-1), acc -> global bf16 agg.
// No MFMA/B-fragment baggage -> natural VGPR ~45; (256,6) cap 80 = 1.8x headroom.
// ============================================================================
__global__ __launch_bounds__(256, 6) void kpconv_aggregate(
    const float* __restrict__ points,
    const float* __restrict__ features,
    const float* __restrict__ output_points,
    const int*   __restrict__ nbr_idx,
    const int*   __restrict__ seg_ids,
    const float* __restrict__ k_points,
    unsigned short* __restrict__ agg_g)
{
    __shared__ int seg_start[TM + 1];

    const int tid = threadIdx.x;
    const int m0  = blockIdx.x * TM;

    if (tid <= TM) {
        const int target = m0 + tid;
        int lo = 0, hi = EDG;
        while (lo < hi) {
            int mid = (lo + hi) >> 1;
            if (seg_ids[mid] < target) lo = mid + 1; else hi = mid;
        }
        seg_start[tid] = lo;
    }
    __syncthreads();

    const int wave = tid >> 6;
    const int lane = tid & 63;
    const int quad = lane >> 4;      // edge slot
    const int l16  = lane & 15;      // kernel point (15 idle -> w=0)
    const int hi5  = lane >> 5;
    const int f    = lane & 31;      // feature channel

    const int myk = l16 < KP ? l16 : (KP - 1);
    const float kpx = k_points[myk * 3 + 0];
    const float kpy = k_points[myk * 3 + 1];
    const float kpz = k_points[myk * 3 + 2];
    const float inv_ext = 1.f / EXTENT;

    for (int l = wave * 4; l < wave * 4 + 4; ++l) {
        float acc[8];
        #pragma unroll
        for (int j = 0; j < 8; ++j) acc[j] = 0.f;

        const int m  = m0 + l;
        const float ox = output_points[m * 3 + 0];
        const float oy = output_points[m * 3 + 1];
        const float oz = output_points[m * 3 + 2];
        const int e0 = seg_start[l], e1 = seg_start[l + 1];

        for (int e = e0; e < e1; e += 4) {
            const int last = e1 - 1;
            const int c1 = e + 1 < e1 ? e + 1 : last;
            const int c2 = e + 2 < e1 ? e + 2 : last;
            const int c3 = e + 3 < e1 ? e + 3 : last;
            const int nb0 = nbr_idx[e];
            const int nb1 = nbr_idx[c1];
            const int nb2 = nbr_idx[c2];
            const int nb3 = nbr_idx[c3];

            const int nb_a   = (quad & 1) ? nb1 : nb0;
            const int nb_b   = (quad & 1) ? nb3 : nb2;
            const int nb_own = (quad & 2) ? nb_b : nb_a;
            const float* pp = points + nb_own * 3;
            const float rx = pp[0] - ox;
            const float ry = pp[1] - oy;
            const float rz = pp[2] - oz;
            const float dx = rx - kpx, dy = ry - kpy, dz = rz - kpz;
            const float d2 = dx * dx + dy * dy + dz * dz;
            float w = 1.f - sqrtf(d2) * inv_ext;
            w = w > 0.f ? w : 0.f;
            const int nvalid = e1 - e;
            if (l16 >= KP || quad >= nvalid) w = 0.f;

            const float fv0 = features[nb0 * FIN + f];
            const float fv1 = features[nb1 * FIN + f];
            const float fv2 = features[nb2 * FIN + f];
            const float fv3 = features[nb3 * FIN + f];

            #pragma unroll
            for (int j = 0; j < 8; ++j) {
                const int kj = 2 * j + hi5;
                acc[j] += __shfl(w, kj)      * fv0;
                acc[j] += __shfl(w, 16 + kj) * fv1;
                acc[j] += __shfl(w, 32 + kj) * fv2;
                acc[j] += __shfl(w, 48 + kj) * fv3;
            }
        }

        unsigned short* dst = agg_g + (size_t)m * KFDIM;
        #pragma unroll
        for (int j = 0; j < 8; ++j) {
            const int idx = lane + 64 * j;          // = k*32 + f
            if (idx < KFDIM) dst[idx] = (unsigned short)f2bf(acc[j]);
        }
    }
}

// ============================================================================
// Kernel B: out = agg[40000x480]_bf16 x W[480x64]. Wave = 32 rows x 16 cols
// (2 MFMAs per k-step), block = 4 waves = 32 rows x 64 cols, grid 1250.
// A-loads: aligned 16B dwordx4 from global; B prefetched (30 VGPR, fine here).
// ============================================================================
__global__ __launch_bounds__(256, 4) void kpconv_gemm(
    const unsigned short* __restrict__ agg_g,
    const float* __restrict__ k_values,
    float* __restrict__ out)
{
    const int tid  = threadIdx.x;
    const int wave = tid >> 6;
    const int lane = tid & 63;
    const int quad = lane >> 4;
    const int l16  = lane & 15;
    const int m0   = blockIdx.x * 32;
    const int bcol = wave * 16 + l16;

    bf16x8 bfr[15];
    #pragma unroll
    for (int s = 0; s < 15; ++s) {
        #pragma unroll
        for (int j = 0; j < 8; ++j)
            bfr[s][j] = f2bf(k_values[(32 * s + quad * 8 + j) * COUT + bcol]);
    }

    const unsigned short* arow0 = agg_g + (size_t)(m0 + l16) * KFDIM + quad * 8;
    const unsigned short* arow1 = arow0 + 16 * KFDIM;

    f32x4 c0 = {0.f, 0.f, 0.f, 0.f};
    f32x4 c1 = {0.f, 0.f, 0.f, 0.f};
    #pragma unroll
    for (int s = 0; s < 15; ++s) {
        const bf16x8 a0 = *(const bf16x8*)(arow0 + 32 * s);
        const bf16x8 a1 = *(const bf16x8*)(arow1 + 32 * s);
        c0 = __builtin_amdgcn_mfma_f32_16x16x32_bf16(a0, bfr[s], c0, 0, 0, 0);
        c1 = __builtin_amdgcn_mfma_f32_16x16x32_bf16(a1, bfr[s], c1, 0, 0, 0);
    }

    // C/D layout: col = lane&15, row = quad*4 + reg
    #pragma unroll
    for (int r = 0; r < 4; ++r) {
        out[(m0 + quad * 4 + r) * COUT + bcol]      = c0[r];
        out[(m0 + 16 + quad * 4 + r) * COUT + bcol] = c1[r];
    }
}

// ============================================================================
// Fallback: R4 fused kernel (92 us steady), used only if ws_size < 38.4 MB.
// ============================================================================
__global__ __launch_bounds__(256, 4) void kpconv_fused(
    const float* __restrict__ points,
    const float* __restrict__ features,
    const float* __restrict__ output_points,
    const int*   __restrict__ nbr_idx,
    const int*   __restrict__ seg_ids,
    const float* __restrict__ k_points,
    const float* __restrict__ k_values,
    float*       __restrict__ out)
{
    __shared__ __align__(16) unsigned short agg[TM * ASTRIDE];
    __shared__ int seg_start[TM + 1];

    const int tid = threadIdx.x;
    const int m0  = blockIdx.x * TM;

    if (tid <= TM) {
        const int target = m0 + tid;
        int lo = 0, hi = EDG;
        while (lo < hi) {
            int mid = (lo + hi) >> 1;
            if (seg_ids[mid] < target) lo = mid + 1; else hi = mid;
        }
        seg_start[tid] = lo;
    }
    __syncthreads();

    const int wave = tid >> 6;
    const int lane = tid & 63;
    const int quad = lane >> 4;
    const int l16  = lane & 15;
    const int hi5  = lane >> 5;
    const int f    = lane & 31;

    const int myk = l16 < KP ? l16 : (KP - 1);
    const float kpx = k_points[myk * 3 + 0];
    const float kpy = k_points[myk * 3 + 1];
    const float kpz = k_points[myk * 3 + 2];
    const float inv_ext = 1.f / EXTENT;

    for (int l = wave * 4; l < wave * 4 + 4; ++l) {
        float acc[8];
        #pragma unroll
        for (int j = 0; j < 8; ++j) acc[j] = 0.f;

        const int m  = m0 + l;
        const float ox = output_points[m * 3 + 0];
        const float oy = output_points[m * 3 + 1];
        const float oz = output_points[m * 3 + 2];
        const int e0 = seg_start[l], e1 = seg_start[l + 1];

        for (int e = e0; e < e1; e += 4) {
            const int last = e1 - 1;
            const int c1 = e + 1 < e1 ? e + 1 : last;
            const int c2 = e + 2 < e1 ? e + 2 : last;
            const int c3 = e + 3 < e1 ? e + 3 : last;
            const int nb0 = nbr_idx[e];
            const int nb1 = nbr_idx[c1];
            const int nb2 = nbr_idx[c2];
            const int nb3 = nbr_idx[c3];

            const int nb_a   = (quad & 1) ? nb1 : nb0;
            const int nb_b   = (quad & 1) ? nb3 : nb2;
            const int nb_own = (quad & 2) ? nb_b : nb_a;
            const float* pp = points + nb_own * 3;
            const float rx = pp[0] - ox;
            const float ry = pp[1] - oy;
            const float rz = pp[2] - oz;
            const float dx = rx - kpx, dy = ry - kpy, dz = rz - kpz;
            const float d2 = dx * dx + dy * dy + dz * dz;
            float w = 1.f - sqrtf(d2) * inv_ext;
            w = w > 0.f ? w : 0.f;
            const int nvalid = e1 - e;
            if (l16 >= KP || quad >= nvalid) w = 0.f;

            const float fv0 = features[nb0 * FIN + f];
            const float fv1 = features[nb1 * FIN + f];
            const float fv2 = features[nb2 * FIN + f];
            const float fv3 = features[nb3 * FIN + f];

            #pragma unroll
            for (int j = 0; j < 8; ++j) {
                const int kj = 2 * j + hi5;
                acc[j] += __shfl(w, kj)      * fv0;
                acc[j] += __shfl(w, 16 + kj) * fv1;
                acc[j] += __shfl(w, 32 + kj) * fv2;
                acc[j] += __shfl(w, 48 + kj) * fv3;
            }
        }

        #pragma unroll
        for (int j = 0; j < 8; ++j) {
            const int idx = lane + 64 * j;
            if (idx < KFDIM) agg[l * ASTRIDE + idx] = (unsigned short)f2bf(acc[j]);
        }
    }

    bf16x8 bfr[15];
    const int bcol = wave * 16 + l16;
    #pragma unroll
    for (int s = 0; s < 15; ++s) {
        #pragma unroll
        for (int j = 0; j < 8; ++j)
            bfr[s][j] = f2bf(k_values[(32 * s + quad * 8 + j) * COUT + bcol]);
    }

    __syncthreads();

    f32x4 c = {0.f, 0.f, 0.f, 0.f};
    #pragma unroll
    for (int s = 0; s < 15; ++s) {
        const bf16x8 af = *(const bf16x8*)&agg[l16 * ASTRIDE + 32 * s + quad * 8];
        c = __builtin_amdgcn_mfma_f32_16x16x32_bf16(af, bfr[s], c, 0, 0, 0);
    }

    #pragma unroll
    for (int r = 0; r < 4; ++r) {
        const int row = quad * 4 + r;
        out[(m0 + row) * COUT + wave * 16 + l16] = c[r];
    }
}

extern "C" void kernel_launch(void* const* d_in, const int* in_sizes, int n_in,
                              void* d_out, int out_size, void* d_ws, size_t ws_size,
                              hipStream_t stream) {
    const float* points        = (const float*)d_in[0];
    const float* features      = (const float*)d_in[1];
    const float* output_points = (const float*)d_in[2];
    const int*   nbr_idx       = (const int*)d_in[3];
    const int*   seg_ids       = (const int*)d_in[4];
    const float* k_points      = (const float*)d_in[5];
    const float* k_values      = (const float*)d_in[6];
    float* out = (float*)d_out;

    const size_t agg_bytes = (size_t)MOUT * KFDIM * sizeof(unsigned short); // 38.4 MB

    if (ws_size >= agg_bytes) {
        unsigned short* agg_g = (unsigned short*)d_ws;
        kpconv_aggregate<<<MOUT / TM, 256, 0, stream>>>(
            points, features, output_points, nbr_idx, seg_ids, k_points, agg_g);
        kpconv_gemm<<<MOUT / 32, 256, 0, stream>>>(agg_g, k_values, out);
    } else {
        kpconv_fused<<<MOUT / TM, 256, 0, stream>>>(
            points, features, output_points, nbr_idx, seg_ids,
            k_points, k_values, out);
    }
}

// Round 7
// 149.354 us; speedup vs baseline: 1.1580x; 1.0566x over previous
//
#include <hip/hip_runtime.h>

typedef __attribute__((ext_vector_type(8))) short bf16x8;
typedef __attribute__((ext_vector_type(4))) float f32x4;

#define NPTS   40000
#define MOUT   40000
#define EDG    500000
#define FIN    32
#define COUT   64
#define KP     15
#define KFDIM  (KP * FIN)          // 480
#define TM     16                  // fused-fallback tile
#define ASTRIDE 488                // fused-fallback LDS stride
#define EXTENT 0.6f

__device__ __forceinline__ short f2bf(float x) {
    union { float f; unsigned u; } v; v.f = x;
    unsigned r = (v.u + 0x7fffu + ((v.u >> 16) & 1u)) >> 16;
    return (short)r;
}

// ============================================================================
// Kernel A (MFMA aggregation): agg[m][k][f] = sum_e w[e,k]*feat[e,f] is a
// (15 x E) x (E x 32) GEMM with kdim = edges. One wave per output point,
// 32 edges per MFMA step (2 mfma: f 0-15 and 16-31).
//   A[m=kpoint][kdim=edge]: m = lane&15, edge = quad*8+j   (same operand
//   pattern kernel B has used correctly since R2)
//   B[kdim=edge][n=f]:      f = lane&15, edge = quad*8+j   -> feature loads
//   are 16-lane-coalesced 64B lines.
// Replaces per-32-edges: 256 ds_bpermute + 256 v_fma + 8-deep serial chunk
// chain with ONE parallel-load step + 2 MFMAs.
// ============================================================================
__global__ __launch_bounds__(256, 4) void kpconv_agg_mfma(
    const float* __restrict__ points,
    const float* __restrict__ features,
    const float* __restrict__ output_points,
    const int*   __restrict__ nbr_idx,
    const int*   __restrict__ seg_ids,
    const float* __restrict__ k_points,
    unsigned short* __restrict__ agg_g)
{
    __shared__ int seg_start[5];

    const int tid  = threadIdx.x;
    const int m0   = blockIdx.x * 4;          // 4 segments (one per wave)

    if (tid <= 4) {
        const int target = m0 + tid;
        int lo = 0, hi = EDG;
        while (lo < hi) {
            int mid = (lo + hi) >> 1;
            if (seg_ids[mid] < target) lo = mid + 1; else hi = mid;
        }
        seg_start[tid] = lo;
    }
    __syncthreads();

    const int wave = tid >> 6;
    const int lane = tid & 63;
    const int quad = lane >> 4;               // kdim group: edges quad*8..+7
    const int l16  = lane & 15;               // kpoint (A) / feature chan (B)

    const int m = m0 + wave;
    const float ox = output_points[m * 3 + 0];
    const float oy = output_points[m * 3 + 1];
    const float oz = output_points[m * 3 + 2];

    const int myk = l16 < KP ? l16 : 0;       // k=15 lanes masked to w=0 below
    const float kpx = k_points[myk * 3 + 0];
    const float kpy = k_points[myk * 3 + 1];
    const float kpz = k_points[myk * 3 + 2];
    const float inv_ext = 1.f / EXTENT;

    const int e0 = seg_start[wave], e1 = seg_start[wave + 1];

    f32x4 c_lo = {0.f, 0.f, 0.f, 0.f};
    f32x4 c_hi = {0.f, 0.f, 0.f, 0.f};

    for (int es = e0; es < e1; es += 32) {
        const int last = e1 - 1;
        const int ebase = es + quad * 8;

        int nb[8];
        #pragma unroll
        for (int j = 0; j < 8; ++j) {
            const int e = ebase + j;
            nb[j] = nbr_idx[e < e1 ? e : last];   // clamp; w=0 for tails
        }

        bf16x8 afrag, blo, bhi;
        #pragma unroll
        for (int j = 0; j < 8; ++j) {
            const float* pp = points + nb[j] * 3;
            const float rx = pp[0] - ox;
            const float ry = pp[1] - oy;
            const float rz = pp[2] - oz;
            const float dx = rx - kpx, dy = ry - kpy, dz = rz - kpz;
            const float d2 = dx * dx + dy * dy + dz * dz;
            float w = 1.f - sqrtf(d2) * inv_ext;
            w = w > 0.f ? w : 0.f;
            if (l16 >= KP || ebase + j >= e1) w = 0.f;
            afrag[j] = f2bf(w);
        }

        #pragma unroll
        for (int j = 0; j < 8; ++j) {
            const float* fp = features + nb[j] * FIN + l16;
            blo[j] = f2bf(fp[0]);
            bhi[j] = f2bf(fp[16]);
        }

        c_lo = __builtin_amdgcn_mfma_f32_16x16x32_bf16(afrag, blo, c_lo, 0, 0, 0);
        c_hi = __builtin_amdgcn_mfma_f32_16x16x32_bf16(afrag, bhi, c_hi, 0, 0, 0);
    }

    // D layout: col = lane&15 (= f), row = quad*4 + r (= kpoint)
    unsigned short* dst = agg_g + (size_t)m * KFDIM;
    #pragma unroll
    for (int r = 0; r < 4; ++r) {
        const int krow = quad * 4 + r;
        if (krow < KP) {
            dst[krow * FIN + l16]      = (unsigned short)f2bf(c_lo[r]);
            dst[krow * FIN + 16 + l16] = (unsigned short)f2bf(c_hi[r]);
        }
    }
}

// ============================================================================
// Kernel B: out = agg[40000x480]_bf16 x W[480x64]. Unchanged from R6 (fast:
// not even in rocprof top-5).
// ============================================================================
__global__ __launch_bounds__(256, 4) void kpconv_gemm(
    const unsigned short* __restrict__ agg_g,
    const float* __restrict__ k_values,
    float* __restrict__ out)
{
    const int tid  = threadIdx.x;
    const int wave = tid >> 6;
    const int lane = tid & 63;
    const int quad = lane >> 4;
    const int l16  = lane & 15;
    const int m0   = blockIdx.x * 32;
    const int bcol = wave * 16 + l16;

    bf16x8 bfr[15];
    #pragma unroll
    for (int s = 0; s < 15; ++s) {
        #pragma unroll
        for (int j = 0; j < 8; ++j)
            bfr[s][j] = f2bf(k_values[(32 * s + quad * 8 + j) * COUT + bcol]);
    }

    const unsigned short* arow0 = agg_g + (size_t)(m0 + l16) * KFDIM + quad * 8;
    const unsigned short* arow1 = arow0 + 16 * KFDIM;

    f32x4 c0 = {0.f, 0.f, 0.f, 0.f};
    f32x4 c1 = {0.f, 0.f, 0.f, 0.f};
    #pragma unroll
    for (int s = 0; s < 15; ++s) {
        const bf16x8 a0 = *(const bf16x8*)(arow0 + 32 * s);
        const bf16x8 a1 = *(const bf16x8*)(arow1 + 32 * s);
        c0 = __builtin_amdgcn_mfma_f32_16x16x32_bf16(a0, bfr[s], c0, 0, 0, 0);
        c1 = __builtin_amdgcn_mfma_f32_16x16x32_bf16(a1, bfr[s], c1, 0, 0, 0);
    }

    #pragma unroll
    for (int r = 0; r < 4; ++r) {
        out[(m0 + quad * 4 + r) * COUT + bcol]      = c0[r];
        out[(m0 + 16 + quad * 4 + r) * COUT + bcol] = c1[r];
    }
}

// ============================================================================
// Fallback: R4 fused kernel, used only if ws_size < 38.4 MB.
// ============================================================================
__global__ __launch_bounds__(256, 4) void kpconv_fused(
    const float* __restrict__ points,
    const float* __restrict__ features,
    const float* __restrict__ output_points,
    const int*   __restrict__ nbr_idx,
    const int*   __restrict__ seg_ids,
    const float* __restrict__ k_points,
    const float* __restrict__ k_values,
    float*       __restrict__ out)
{
    __shared__ __align__(16) unsigned short agg[TM * ASTRIDE];
    __shared__ int seg_start[TM + 1];

    const int tid = threadIdx.x;
    const int m0  = blockIdx.x * TM;

    if (tid <= TM) {
        const int target = m0 + tid;
        int lo = 0, hi = EDG;
        while (lo < hi) {
            int mid = (lo + hi) >> 1;
            if (seg_ids[mid] < target) lo = mid + 1; else hi = mid;
        }
        seg_start[tid] = lo;
    }
    __syncthreads();

    const int wave = tid >> 6;
    const int lane = tid & 63;
    const int quad = lane >> 4;
    const int l16  = lane & 15;
    const int hi5  = lane >> 5;
    const int f    = lane & 31;

    const int myk = l16 < KP ? l16 : (KP - 1);
    const float kpx = k_points[myk * 3 + 0];
    const float kpy = k_points[myk * 3 + 1];
    const float kpz = k_points[myk * 3 + 2];
    const float inv_ext = 1.f / EXTENT;

    for (int l = wave * 4; l < wave * 4 + 4; ++l) {
        float acc[8];
        #pragma unroll
        for (int j = 0; j < 8; ++j) acc[j] = 0.f;

        const int m  = m0 + l;
        const float ox = output_points[m * 3 + 0];
        const float oy = output_points[m * 3 + 1];
        const float oz = output_points[m * 3 + 2];
        const int e0 = seg_start[l], e1 = seg_start[l + 1];

        for (int e = e0; e < e1; e += 4) {
            const int last = e1 - 1;
            const int c1 = e + 1 < e1 ? e + 1 : last;
            const int c2 = e + 2 < e1 ? e + 2 : last;
            const int c3 = e + 3 < e1 ? e + 3 : last;
            const int nb0 = nbr_idx[e];
            const int nb1 = nbr_idx[c1];
            const int nb2 = nbr_idx[c2];
            const int nb3 = nbr_idx[c3];

            const int nb_a   = (quad & 1) ? nb1 : nb0;
            const int nb_b   = (quad & 1) ? nb3 : nb2;
            const int nb_own = (quad & 2) ? nb_b : nb_a;
            const float* pp = points + nb_own * 3;
            const float rx = pp[0] - ox;
            const float ry = pp[1] - oy;
            const float rz = pp[2] - oz;
            const float dx = rx - kpx, dy = ry - kpy, dz = rz - kpz;
            const float d2 = dx * dx + dy * dy + dz * dz;
            float w = 1.f - sqrtf(d2) * inv_ext;
            w = w > 0.f ? w : 0.f;
            const int nvalid = e1 - e;
            if (l16 >= KP || quad >= nvalid) w = 0.f;

            const float fv0 = features[nb0 * FIN + f];
            const float fv1 = features[nb1 * FIN + f];
            const float fv2 = features[nb2 * FIN + f];
            const float fv3 = features[nb3 * FIN + f];

            #pragma unroll
            for (int j = 0; j < 8; ++j) {
                const int kj = 2 * j + hi5;
                acc[j] += __shfl(w, kj)      * fv0;
                acc[j] += __shfl(w, 16 + kj) * fv1;
                acc[j] += __shfl(w, 32 + kj) * fv2;
                acc[j] += __shfl(w, 48 + kj) * fv3;
            }
        }

        #pragma unroll
        for (int j = 0; j < 8; ++j) {
            const int idx = lane + 64 * j;
            if (idx < KFDIM) agg[l * ASTRIDE + idx] = (unsigned short)f2bf(acc[j]);
        }
    }

    bf16x8 bfr[15];
    const int bcol = wave * 16 + l16;
    #pragma unroll
    for (int s = 0; s < 15; ++s) {
        #pragma unroll
        for (int j = 0; j < 8; ++j)
            bfr[s][j] = f2bf(k_values[(32 * s + quad * 8 + j) * COUT + bcol]);
    }

    __syncthreads();

    f32x4 c = {0.f, 0.f, 0.f, 0.f};
    #pragma unroll
    for (int s = 0; s < 15; ++s) {
        const bf16x8 af = *(const bf16x8*)&agg[l16 * ASTRIDE + 32 * s + quad * 8];
        c = __builtin_amdgcn_mfma_f32_16x16x32_bf16(af, bfr[s], c, 0, 0, 0);
    }

    #pragma unroll
    for (int r = 0; r < 4; ++r) {
        const int row = quad * 4 + r;
        out[(m0 + row) * COUT + wave * 16 + l16] = c[r];
    }
}

extern "C" void kernel_launch(void* const* d_in, const int* in_sizes, int n_in,
                              void* d_out, int out_size, void* d_ws, size_t ws_size,
                              hipStream_t stream) {
    const float* points        = (const float*)d_in[0];
    const float* features      = (const float*)d_in[1];
    const float* output_points = (const float*)d_in[2];
    const int*   nbr_idx       = (const int*)d_in[3];
    const int*   seg_ids       = (const int*)d_in[4];
    const float* k_points      = (const float*)d_in[5];
    const float* k_values      = (const float*)d_in[6];
    float* out = (float*)d_out;

    const size_t agg_bytes = (size_t)MOUT * KFDIM * sizeof(unsigned short); // 38.4 MB

    if (ws_size >= agg_bytes) {
        unsigned short* agg_g = (unsigned short*)d_ws;
        kpconv_agg_mfma<<<MOUT / 4, 256, 0, stream>>>(
            points, features, output_points, nbr_idx, seg_ids, k_points, agg_g);
        kpconv_gemm<<<MOUT / 32, 256, 0, stream>>>(agg_g, k_values, out);
    } else {
        kpconv_fused<<<MOUT / TM, 256, 0, stream>>>(
            points, features, output_points, nbr_idx, seg_ids,
            k_points, k_values, out);
    }
}

// Round 8
// 143.984 us; speedup vs baseline: 1.2012x; 1.0373x over previous
//
#include <hip/hip_runtime.h>

typedef __attribute__((ext_vector_type(8))) short bf16x8;
typedef __attribute__((ext_vector_type(4))) float f32x4;
typedef __attribute__((ext_vector_type(4))) _Float16 f16x4;

#define NPTS   40000
#define MOUT   40000
#define EDG    500000
#define FIN    32
#define COUT   64
#define KP     15
#define KFDIM  (KP * FIN)          // 480
#define TM     16                  // fused-fallback tile
#define ASTRIDE 488                // fused-fallback LDS stride
#define EXTENT 0.6f

__device__ __forceinline__ short f2bf(float x) {
    union { float f; unsigned u; } v; v.f = x;
    unsigned r = (v.u + 0x7fffu + ((v.u >> 16) & 1u)) >> 16;
    return (short)r;
}

// ============================================================================
// Kernel A0: one-shot features f32 -> f16 (so the hot gather loop does 2B
// loads with ZERO per-edge conversion VALU). 1.28M elems.
// ============================================================================
__global__ __launch_bounds__(256) void feat_to_f16(
    const float* __restrict__ features, _Float16* __restrict__ feat_h)
{
    const int i = (blockIdx.x * 256 + threadIdx.x) * 4;
    const float4 v = *(const float4*)(features + i);
    feat_h[i + 0] = (_Float16)v.x;
    feat_h[i + 1] = (_Float16)v.y;
    feat_h[i + 2] = (_Float16)v.z;
    feat_h[i + 3] = (_Float16)v.w;
}

// ============================================================================
// Kernel A: MFMA aggregation, K=16 steps (f16). agg[m][k][f] = sum_e w*feat.
// Mean segment = 12.5 edges -> K=16 halves the masked waste of R7's K=32.
//   A[m=kpoint][kdim=edge]: m = lane&15, edge = quad*4+j (j=0..3)
//   B[kdim=edge][n=f]:      f = lane&15, edge = quad*4+j
//   D: col = lane&15 (=f), row = quad*4+r (=kpoint)  [shape-determined layout]
// (256,8): cap 64 VGPR vs natural ~32 measured in R7 — 2x headroom, no-spill
// (R3/R5 lesson: never cap below ~1.3x natural).
// ============================================================================
__global__ __launch_bounds__(256, 8) void kpconv_agg_mfma16(
    const float* __restrict__ points,
    const _Float16* __restrict__ feat_h,
    const float* __restrict__ output_points,
    const int*   __restrict__ nbr_idx,
    const int*   __restrict__ seg_ids,
    const float* __restrict__ k_points,
    unsigned short* __restrict__ agg_g)
{
    __shared__ int seg_start[5];

    const int tid  = threadIdx.x;
    const int m0   = blockIdx.x * 4;          // 4 segments (one per wave)

    if (tid <= 4) {
        const int target = m0 + tid;
        int lo = 0, hi = EDG;
        while (lo < hi) {
            int mid = (lo + hi) >> 1;
            if (seg_ids[mid] < target) lo = mid + 1; else hi = mid;
        }
        seg_start[tid] = lo;
    }
    __syncthreads();

    const int wave = tid >> 6;
    const int lane = tid & 63;
    const int quad = lane >> 4;               // kdim group: edges quad*4..+3
    const int l16  = lane & 15;               // kpoint (A) / feature chan (B)

    const int m = m0 + wave;
    const float ox = output_points[m * 3 + 0];
    const float oy = output_points[m * 3 + 1];
    const float oz = output_points[m * 3 + 2];

    const int myk = l16 < KP ? l16 : 0;       // k=15 lanes masked to w=0 below
    const float kpx = k_points[myk * 3 + 0];
    const float kpy = k_points[myk * 3 + 1];
    const float kpz = k_points[myk * 3 + 2];
    const float inv_ext = 1.f / EXTENT;

    const int e0 = seg_start[wave], e1 = seg_start[wave + 1];

    f32x4 c_lo = {0.f, 0.f, 0.f, 0.f};
    f32x4 c_hi = {0.f, 0.f, 0.f, 0.f};

    for (int es = e0; es < e1; es += 16) {
        const int last = e1 - 1;
        const int ebase = es + quad * 4;

        int nb[4];
        #pragma unroll
        for (int j = 0; j < 4; ++j) {
            const int e = ebase + j;
            nb[j] = nbr_idx[e < e1 ? e : last];   // clamp; w=0 for tails
        }

        f16x4 afrag, blo, bhi;
        #pragma unroll
        for (int j = 0; j < 4; ++j) {
            const float* pp = points + nb[j] * 3;
            const float rx = pp[0] - ox;
            const float ry = pp[1] - oy;
            const float rz = pp[2] - oz;
            const float dx = rx - kpx, dy = ry - kpy, dz = rz - kpz;
            const float d2 = dx * dx + dy * dy + dz * dz;
            float w = 1.f - sqrtf(d2) * inv_ext;
            w = w > 0.f ? w : 0.f;
            if (l16 >= KP || ebase + j >= e1) w = 0.f;
            afrag[j] = (_Float16)w;
        }

        #pragma unroll
        for (int j = 0; j < 4; ++j) {
            const _Float16* fp = feat_h + nb[j] * FIN + l16;
            blo[j] = fp[0];
            bhi[j] = fp[16];
        }

        c_lo = __builtin_amdgcn_mfma_f32_16x16x16f16(afrag, blo, c_lo, 0, 0, 0);
        c_hi = __builtin_amdgcn_mfma_f32_16x16x16f16(afrag, bhi, c_hi, 0, 0, 0);
    }

    // D layout: col = lane&15 (= f), row = quad*4 + r (= kpoint)
    unsigned short* dst = agg_g + (size_t)m * KFDIM;
    #pragma unroll
    for (int r = 0; r < 4; ++r) {
        const int krow = quad * 4 + r;
        if (krow < KP) {
            dst[krow * FIN + l16]      = (unsigned short)f2bf(c_lo[r]);
            dst[krow * FIN + 16 + l16] = (unsigned short)f2bf(c_hi[r]);
        }
    }
}

// ============================================================================
// Kernel A-mid (fallback if ws can't fit feat_h): R7's K=32 float-feature
// MFMA aggregation, unchanged.
// ============================================================================
__global__ __launch_bounds__(256, 4) void kpconv_agg_mfma(
    const float* __restrict__ points,
    const float* __restrict__ features,
    const float* __restrict__ output_points,
    const int*   __restrict__ nbr_idx,
    const int*   __restrict__ seg_ids,
    const float* __restrict__ k_points,
    unsigned short* __restrict__ agg_g)
{
    __shared__ int seg_start[5];

    const int tid  = threadIdx.x;
    const int m0   = blockIdx.x * 4;

    if (tid <= 4) {
        const int target = m0 + tid;
        int lo = 0, hi = EDG;
        while (lo < hi) {
            int mid = (lo + hi) >> 1;
            if (seg_ids[mid] < target) lo = mid + 1; else hi = mid;
        }
        seg_start[tid] = lo;
    }
    __syncthreads();

    const int wave = tid >> 6;
    const int lane = tid & 63;
    const int quad = lane >> 4;
    const int l16  = lane & 15;

    const int m = m0 + wave;
    const float ox = output_points[m * 3 + 0];
    const float oy = output_points[m * 3 + 1];
    const float oz = output_points[m * 3 + 2];

    const int myk = l16 < KP ? l16 : 0;
    const float kpx = k_points[myk * 3 + 0];
    const float kpy = k_points[myk * 3 + 1];
    const float kpz = k_points[myk * 3 + 2];
    const float inv_ext = 1.f / EXTENT;

    const int e0 = seg_start[wave], e1 = seg_start[wave + 1];

    f32x4 c_lo = {0.f, 0.f, 0.f, 0.f};
    f32x4 c_hi = {0.f, 0.f, 0.f, 0.f};

    for (int es = e0; es < e1; es += 32) {
        const int last = e1 - 1;
        const int ebase = es + quad * 8;

        int nb[8];
        #pragma unroll
        for (int j = 0; j < 8; ++j) {
            const int e = ebase + j;
            nb[j] = nbr_idx[e < e1 ? e : last];
        }

        bf16x8 afrag, blo, bhi;
        #pragma unroll
        for (int j = 0; j < 8; ++j) {
            const float* pp = points + nb[j] * 3;
            const float rx = pp[0] - ox;
            const float ry = pp[1] - oy;
            const float rz = pp[2] - oz;
            const float dx = rx - kpx, dy = ry - kpy, dz = rz - kpz;
            const float d2 = dx * dx + dy * dy + dz * dz;
            float w = 1.f - sqrtf(d2) * inv_ext;
            w = w > 0.f ? w : 0.f;
            if (l16 >= KP || ebase + j >= e1) w = 0.f;
            afrag[j] = f2bf(w);
        }

        #pragma unroll
        for (int j = 0; j < 8; ++j) {
            const float* fp = features + nb[j] * FIN + l16;
            blo[j] = f2bf(fp[0]);
            bhi[j] = f2bf(fp[16]);
        }

        c_lo = __builtin_amdgcn_mfma_f32_16x16x32_bf16(afrag, blo, c_lo, 0, 0, 0);
        c_hi = __builtin_amdgcn_mfma_f32_16x16x32_bf16(afrag, bhi, c_hi, 0, 0, 0);
    }

    unsigned short* dst = agg_g + (size_t)m * KFDIM;
    #pragma unroll
    for (int r = 0; r < 4; ++r) {
        const int krow = quad * 4 + r;
        if (krow < KP) {
            dst[krow * FIN + l16]      = (unsigned short)f2bf(c_lo[r]);
            dst[krow * FIN + 16 + l16] = (unsigned short)f2bf(c_hi[r]);
        }
    }
}

// ============================================================================
// Kernel B: out = agg[40000x480]_bf16 x W[480x64]. Unchanged (fast).
// ============================================================================
__global__ __launch_bounds__(256, 4) void kpconv_gemm(
    const unsigned short* __restrict__ agg_g,
    const float* __restrict__ k_values,
    float* __restrict__ out)
{
    const int tid  = threadIdx.x;
    const int wave = tid >> 6;
    const int lane = tid & 63;
    const int quad = lane >> 4;
    const int l16  = lane & 15;
    const int m0   = blockIdx.x * 32;
    const int bcol = wave * 16 + l16;

    bf16x8 bfr[15];
    #pragma unroll
    for (int s = 0; s < 15; ++s) {
        #pragma unroll
        for (int j = 0; j < 8; ++j)
            bfr[s][j] = f2bf(k_values[(32 * s + quad * 8 + j) * COUT + bcol]);
    }

    const unsigned short* arow0 = agg_g + (size_t)(m0 + l16) * KFDIM + quad * 8;
    const unsigned short* arow1 = arow0 + 16 * KFDIM;

    f32x4 c0 = {0.f, 0.f, 0.f, 0.f};
    f32x4 c1 = {0.f, 0.f, 0.f, 0.f};
    #pragma unroll
    for (int s = 0; s < 15; ++s) {
        const bf16x8 a0 = *(const bf16x8*)(arow0 + 32 * s);
        const bf16x8 a1 = *(const bf16x8*)(arow1 + 32 * s);
        c0 = __builtin_amdgcn_mfma_f32_16x16x32_bf16(a0, bfr[s], c0, 0, 0, 0);
        c1 = __builtin_amdgcn_mfma_f32_16x16x32_bf16(a1, bfr[s], c1, 0, 0, 0);
    }

    #pragma unroll
    for (int r = 0; r < 4; ++r) {
        out[(m0 + quad * 4 + r) * COUT + bcol]      = c0[r];
        out[(m0 + 16 + quad * 4 + r) * COUT + bcol] = c1[r];
    }
}

// ============================================================================
// Fallback: R4 fused kernel, used only if ws_size < 38.4 MB.
// ============================================================================
__global__ __launch_bounds__(256, 4) void kpconv_fused(
    const float* __restrict__ points,
    const float* __restrict__ features,
    const float* __restrict__ output_points,
    const int*   __restrict__ nbr_idx,
    const int*   __restrict__ seg_ids,
    const float* __restrict__ k_points,
    const float* __restrict__ k_values,
    float*       __restrict__ out)
{
    __shared__ __align__(16) unsigned short agg[TM * ASTRIDE];
    __shared__ int seg_start[TM + 1];

    const int tid = threadIdx.x;
    const int m0  = blockIdx.x * TM;

    if (tid <= TM) {
        const int target = m0 + tid;
        int lo = 0, hi = EDG;
        while (lo < hi) {
            int mid = (lo + hi) >> 1;
            if (seg_ids[mid] < target) lo = mid + 1; else hi = mid;
        }
        seg_start[tid] = lo;
    }
    __syncthreads();

    const int wave = tid >> 6;
    const int lane = tid & 63;
    const int quad = lane >> 4;
    const int l16  = lane & 15;
    const int hi5  = lane >> 5;
    const int f    = lane & 31;

    const int myk = l16 < KP ? l16 : (KP - 1);
    const float kpx = k_points[myk * 3 + 0];
    const float kpy = k_points[myk * 3 + 1];
    const float kpz = k_points[myk * 3 + 2];
    const float inv_ext = 1.f / EXTENT;

    for (int l = wave * 4; l < wave * 4 + 4; ++l) {
        float acc[8];
        #pragma unroll
        for (int j = 0; j < 8; ++j) acc[j] = 0.f;

        const int m  = m0 + l;
        const float ox = output_points[m * 3 + 0];
        const float oy = output_points[m * 3 + 1];
        const float oz = output_points[m * 3 + 2];
        const int e0 = seg_start[l], e1 = seg_start[l + 1];

        for (int e = e0; e < e1; e += 4) {
            const int last = e1 - 1;
            const int c1 = e + 1 < e1 ? e + 1 : last;
            const int c2 = e + 2 < e1 ? e + 2 : last;
            const int c3 = e + 3 < e1 ? e + 3 : last;
            const int nb0 = nbr_idx[e];
            const int nb1 = nbr_idx[c1];
            const int nb2 = nbr_idx[c2];
            const int nb3 = nbr_idx[c3];

            const int nb_a   = (quad & 1) ? nb1 : nb0;
            const int nb_b   = (quad & 1) ? nb3 : nb2;
            const int nb_own = (quad & 2) ? nb_b : nb_a;
            const float* pp = points + nb_own * 3;
            const float rx = pp[0] - ox;
            const float ry = pp[1] - oy;
            const float rz = pp[2] - oz;
            const float dx = rx - kpx, dy = ry - kpy, dz = rz - kpz;
            const float d2 = dx * dx + dy * dy + dz * dz;
            float w = 1.f - sqrtf(d2) * inv_ext;
            w = w > 0.f ? w : 0.f;
            const int nvalid = e1 - e;
            if (l16 >= KP || quad >= nvalid) w = 0.f;

            const float fv0 = features[nb0 * FIN + f];
            const float fv1 = features[nb1 * FIN + f];
            const float fv2 = features[nb2 * FIN + f];
            const float fv3 = features[nb3 * FIN + f];

            #pragma unroll
            for (int j = 0; j < 8; ++j) {
                const int kj = 2 * j + hi5;
                acc[j] += __shfl(w, kj)      * fv0;
                acc[j] += __shfl(w, 16 + kj) * fv1;
                acc[j] += __shfl(w, 32 + kj) * fv2;
                acc[j] += __shfl(w, 48 + kj) * fv3;
            }
        }

        #pragma unroll
        for (int j = 0; j < 8; ++j) {
            const int idx = lane + 64 * j;
            if (idx < KFDIM) agg[l * ASTRIDE + idx] = (unsigned short)f2bf(acc[j]);
        }
    }

    bf16x8 bfr[15];
    const int bcol = wave * 16 + l16;
    #pragma unroll
    for (int s = 0; s < 15; ++s) {
        #pragma unroll
        for (int j = 0; j < 8; ++j)
            bfr[s][j] = f2bf(k_values[(32 * s + quad * 8 + j) * COUT + bcol]);
    }

    __syncthreads();

    f32x4 c = {0.f, 0.f, 0.f, 0.f};
    #pragma unroll
    for (int s = 0; s < 15; ++s) {
        const bf16x8 af = *(const bf16x8*)&agg[l16 * ASTRIDE + 32 * s + quad * 8];
        c = __builtin_amdgcn_mfma_f32_16x16x32_bf16(af, bfr[s], c, 0, 0, 0);
    }

    #pragma unroll
    for (int r = 0; r < 4; ++r) {
        const int row = quad * 4 + r;
        out[(m0 + row) * COUT + wave * 16 + l16] = c[r];
    }
}

extern "C" void kernel_launch(void* const* d_in, const int* in_sizes, int n_in,
                              void* d_out, int out_size, void* d_ws, size_t ws_size,
                              hipStream_t stream) {
    const float* points        = (const float*)d_in[0];
    const float* features      = (const float*)d_in[1];
    const float* output_points = (const float*)d_in[2];
    const int*   nbr_idx       = (const int*)d_in[3];
    const int*   seg_ids       = (const int*)d_in[4];
    const float* k_points      = (const float*)d_in[5];
    const float* k_values      = (const float*)d_in[6];
    float* out = (float*)d_out;

    const size_t feat_bytes = (size_t)NPTS * FIN * sizeof(_Float16);          // 2.56 MB
    const size_t agg_bytes  = (size_t)MOUT * KFDIM * sizeof(unsigned short);  // 38.4 MB

    if (ws_size >= feat_bytes + agg_bytes) {
        _Float16* feat_h = (_Float16*)d_ws;
        unsigned short* agg_g = (unsigned short*)((char*)d_ws + feat_bytes);
        feat_to_f16<<<NPTS * FIN / 1024, 256, 0, stream>>>(features, feat_h);
        kpconv_agg_mfma16<<<MOUT / 4, 256, 0, stream>>>(
            points, feat_h, output_points, nbr_idx, seg_ids, k_points, agg_g);
        kpconv_gemm<<<MOUT / 32, 256, 0, stream>>>(agg_g, k_values, out);
    } else if (ws_size >= agg_bytes) {
        unsigned short* agg_g = (unsigned short*)d_ws;
        kpconv_agg_mfma<<<MOUT / 4, 256, 0, stream>>>(
            points, features, output_points, nbr_idx, seg_ids, k_points, agg_g);
        kpconv_gemm<<<MOUT / 32, 256, 0, stream>>>(agg_g, k_values, out);
    } else {
        kpconv_fused<<<MOUT / TM, 256, 0, stream>>>(
            points, features, output_points, nbr_idx, seg_ids,
            k_points, k_values, out);
    }
}

// Round 9
// 126.786 us; speedup vs baseline: 1.3642x; 1.1356x over previous
//
#include <hip/hip_runtime.h>

typedef __attribute__((ext_vector_type(8))) short bf16x8;
typedef __attribute__((ext_vector_type(4))) float f32x4;
typedef __attribute__((ext_vector_type(4))) _Float16 f16x4;

#define NPTS   40000
#define MOUT   40000
#define EDG    500000
#define FIN    32
#define COUT   64
#define KP     15
#define KFDIM  (KP * FIN)          // 480
#define TM     16                  // fused-fallback tile
#define ASTRIDE 488                // fused-fallback LDS stride
#define EXTENT 0.6f

__device__ __forceinline__ short f2bf(float x) {
    union { float f; unsigned u; } v; v.f = x;
    unsigned r = (v.u + 0x7fffu + ((v.u >> 16) & 1u)) >> 16;
    return (short)r;
}

// ============================================================================
// Preprocess 1: features f32 -> f16 (2B gathers, no per-edge convert VALU).
// ============================================================================
__global__ __launch_bounds__(256) void feat_to_f16(
    const float* __restrict__ features, _Float16* __restrict__ feat_h)
{
    const int i = (blockIdx.x * 256 + threadIdx.x) * 4;
    const float4 v = *(const float4*)(features + i);
    feat_h[i + 0] = (_Float16)v.x;
    feat_h[i + 1] = (_Float16)v.y;
    feat_h[i + 2] = (_Float16)v.z;
    feat_h[i + 3] = (_Float16)v.w;
}

// ============================================================================
// Preprocess 2: pad points to float4 -> each edge's coords are ONE dwordx4
// (was 3 separate dword gathers = half of all VMEM in the R8 hot loop).
// ============================================================================
__global__ __launch_bounds__(256) void pts_to_f4(
    const float* __restrict__ pts, float4* __restrict__ p4)
{
    const int i = blockIdx.x * 256 + threadIdx.x;
    if (i < NPTS) {
        const float* p = pts + 3 * i;
        p4[i] = make_float4(p[0], p[1], p[2], 0.f);
    }
}

// ============================================================================
// Preprocess 3: CSR row starts via scatter. Thread e writes row_start[m]=e
// for m in (seg[e-1], seg[e]] — disjoint ranges, no atomics. Replaces the
// per-block 19-deep DEPENDENT binary-search chain (~4000 cyc x 10000 blocks
// — R8's actual bottleneck: nothing else was saturated).
// ============================================================================
__global__ __launch_bounds__(256) void build_row_starts(
    const int* __restrict__ seg_ids, int* __restrict__ row_start)
{
    const int e = blockIdx.x * 256 + threadIdx.x;
    if (e >= EDG) return;
    const int cur  = seg_ids[e];
    const int prev = (e == 0) ? -1 : seg_ids[e - 1];
    for (int m = prev + 1; m <= cur; ++m) row_start[m] = e;
    if (e == EDG - 1)
        for (int m = cur + 1; m <= MOUT; ++m) row_start[m] = EDG;
}

// ============================================================================
// Kernel A: MFMA aggregation, K=16 (f16). One wave per segment; e0/e1 read
// flat from row_start (2 loads, no LDS, no __syncthreads).
//   A[m=kpoint][k=edge]: m=lane&15, edge=quad*4+j ; B[edge][f]: f=lane&15
//   D: col=lane&15 (=f), row=quad*4+r (=kpoint)
// ============================================================================
__global__ __launch_bounds__(256, 8) void kpconv_agg_mfma16(
    const float4* __restrict__ points4,
    const _Float16* __restrict__ feat_h,
    const float* __restrict__ output_points,
    const int*   __restrict__ nbr_idx,
    const int*   __restrict__ row_start,
    const float* __restrict__ k_points,
    unsigned short* __restrict__ agg_g)
{
    const int tid  = threadIdx.x;
    const int wave = tid >> 6;
    const int lane = tid & 63;
    const int quad = lane >> 4;
    const int l16  = lane & 15;

    const int m = blockIdx.x * 4 + wave;
    const int e0 = row_start[m], e1 = row_start[m + 1];

    const float ox = output_points[m * 3 + 0];
    const float oy = output_points[m * 3 + 1];
    const float oz = output_points[m * 3 + 2];

    const int myk = l16 < KP ? l16 : 0;
    const float kpx = k_points[myk * 3 + 0];
    const float kpy = k_points[myk * 3 + 1];
    const float kpz = k_points[myk * 3 + 2];
    const float inv_ext = 1.f / EXTENT;

    f32x4 c_lo = {0.f, 0.f, 0.f, 0.f};
    f32x4 c_hi = {0.f, 0.f, 0.f, 0.f};

    for (int es = e0; es < e1; es += 16) {
        const int last = e1 - 1;
        const int ebase = es + quad * 4;

        int nb[4];
        #pragma unroll
        for (int j = 0; j < 4; ++j) {
            const int e = ebase + j;
            nb[j] = nbr_idx[e < e1 ? e : last];   // clamp; w=0 for tails
        }

        f16x4 afrag, blo, bhi;
        #pragma unroll
        for (int j = 0; j < 4; ++j) {
            const float4 p = points4[nb[j]];
            const float rx = p.x - ox;
            const float ry = p.y - oy;
            const float rz = p.z - oz;
            const float dx = rx - kpx, dy = ry - kpy, dz = rz - kpz;
            const float d2 = dx * dx + dy * dy + dz * dz;
            float w = 1.f - sqrtf(d2) * inv_ext;
            w = w > 0.f ? w : 0.f;
            if (l16 >= KP || ebase + j >= e1) w = 0.f;
            afrag[j] = (_Float16)w;
        }

        #pragma unroll
        for (int j = 0; j < 4; ++j) {
            const _Float16* fp = feat_h + nb[j] * FIN + l16;
            blo[j] = fp[0];
            bhi[j] = fp[16];
        }

        c_lo = __builtin_amdgcn_mfma_f32_16x16x16f16(afrag, blo, c_lo, 0, 0, 0);
        c_hi = __builtin_amdgcn_mfma_f32_16x16x16f16(afrag, bhi, c_hi, 0, 0, 0);
    }

    unsigned short* dst = agg_g + (size_t)m * KFDIM;
    #pragma unroll
    for (int r = 0; r < 4; ++r) {
        const int krow = quad * 4 + r;
        if (krow < KP) {
            dst[krow * FIN + l16]      = (unsigned short)f2bf(c_lo[r]);
            dst[krow * FIN + 16 + l16] = (unsigned short)f2bf(c_hi[r]);
        }
    }
}

// ============================================================================
// Kernel B: out = agg[40000x480]_bf16 x W[480x64]. Unchanged (fast).
// ============================================================================
__global__ __launch_bounds__(256, 4) void kpconv_gemm(
    const unsigned short* __restrict__ agg_g,
    const float* __restrict__ k_values,
    float* __restrict__ out)
{
    const int tid  = threadIdx.x;
    const int wave = tid >> 6;
    const int lane = tid & 63;
    const int quad = lane >> 4;
    const int l16  = lane & 15;
    const int m0   = blockIdx.x * 32;
    const int bcol = wave * 16 + l16;

    bf16x8 bfr[15];
    #pragma unroll
    for (int s = 0; s < 15; ++s) {
        #pragma unroll
        for (int j = 0; j < 8; ++j)
            bfr[s][j] = f2bf(k_values[(32 * s + quad * 8 + j) * COUT + bcol]);
    }

    const unsigned short* arow0 = agg_g + (size_t)(m0 + l16) * KFDIM + quad * 8;
    const unsigned short* arow1 = arow0 + 16 * KFDIM;

    f32x4 c0 = {0.f, 0.f, 0.f, 0.f};
    f32x4 c1 = {0.f, 0.f, 0.f, 0.f};
    #pragma unroll
    for (int s = 0; s < 15; ++s) {
        const bf16x8 a0 = *(const bf16x8*)(arow0 + 32 * s);
        const bf16x8 a1 = *(const bf16x8*)(arow1 + 32 * s);
        c0 = __builtin_amdgcn_mfma_f32_16x16x32_bf16(a0, bfr[s], c0, 0, 0, 0);
        c1 = __builtin_amdgcn_mfma_f32_16x16x32_bf16(a1, bfr[s], c1, 0, 0, 0);
    }

    #pragma unroll
    for (int r = 0; r < 4; ++r) {
        out[(m0 + quad * 4 + r) * COUT + bcol]      = c0[r];
        out[(m0 + 16 + quad * 4 + r) * COUT + bcol] = c1[r];
    }
}

// ============================================================================
// Fallback (ws too small for the full path): R7's K=32 MFMA aggregation with
// in-kernel binary search, f32 features.
// ============================================================================
__global__ __launch_bounds__(256, 4) void kpconv_agg_mfma(
    const float* __restrict__ points,
    const float* __restrict__ features,
    const float* __restrict__ output_points,
    const int*   __restrict__ nbr_idx,
    const int*   __restrict__ seg_ids,
    const float* __restrict__ k_points,
    unsigned short* __restrict__ agg_g)
{
    __shared__ int seg_start[5];

    const int tid  = threadIdx.x;
    const int m0   = blockIdx.x * 4;

    if (tid <= 4) {
        const int target = m0 + tid;
        int lo = 0, hi = EDG;
        while (lo < hi) {
            int mid = (lo + hi) >> 1;
            if (seg_ids[mid] < target) lo = mid + 1; else hi = mid;
        }
        seg_start[tid] = lo;
    }
    __syncthreads();

    const int wave = tid >> 6;
    const int lane = tid & 63;
    const int quad = lane >> 4;
    const int l16  = lane & 15;

    const int m = m0 + wave;
    const float ox = output_points[m * 3 + 0];
    const float oy = output_points[m * 3 + 1];
    const float oz = output_points[m * 3 + 2];

    const int myk = l16 < KP ? l16 : 0;
    const float kpx = k_points[myk * 3 + 0];
    const float kpy = k_points[myk * 3 + 1];
    const float kpz = k_points[myk * 3 + 2];
    const float inv_ext = 1.f / EXTENT;

    const int e0 = seg_start[wave], e1 = seg_start[wave + 1];

    f32x4 c_lo = {0.f, 0.f, 0.f, 0.f};
    f32x4 c_hi = {0.f, 0.f, 0.f, 0.f};

    for (int es = e0; es < e1; es += 32) {
        const int last = e1 - 1;
        const int ebase = es + quad * 8;

        int nb[8];
        #pragma unroll
        for (int j = 0; j < 8; ++j) {
            const int e = ebase + j;
            nb[j] = nbr_idx[e < e1 ? e : last];
        }

        bf16x8 afrag, blo, bhi;
        #pragma unroll
        for (int j = 0; j < 8; ++j) {
            const float* pp = points + nb[j] * 3;
            const float rx = pp[0] - ox;
            const float ry = pp[1] - oy;
            const float rz = pp[2] - oz;
            const float dx = rx - kpx, dy = ry - kpy, dz = rz - kpz;
            const float d2 = dx * dx + dy * dy + dz * dz;
            float w = 1.f - sqrtf(d2) * inv_ext;
            w = w > 0.f ? w : 0.f;
            if (l16 >= KP || ebase + j >= e1) w = 0.f;
            afrag[j] = f2bf(w);
        }

        #pragma unroll
        for (int j = 0; j < 8; ++j) {
            const float* fp = features + nb[j] * FIN + l16;
            blo[j] = f2bf(fp[0]);
            bhi[j] = f2bf(fp[16]);
        }

        c_lo = __builtin_amdgcn_mfma_f32_16x16x32_bf16(afrag, blo, c_lo, 0, 0, 0);
        c_hi = __builtin_amdgcn_mfma_f32_16x16x32_bf16(afrag, bhi, c_hi, 0, 0, 0);
    }

    unsigned short* dst = agg_g + (size_t)m * KFDIM;
    #pragma unroll
    for (int r = 0; r < 4; ++r) {
        const int krow = quad * 4 + r;
        if (krow < KP) {
            dst[krow * FIN + l16]      = (unsigned short)f2bf(c_lo[r]);
            dst[krow * FIN + 16 + l16] = (unsigned short)f2bf(c_hi[r]);
        }
    }
}

extern "C" void kernel_launch(void* const* d_in, const int* in_sizes, int n_in,
                              void* d_out, int out_size, void* d_ws, size_t ws_size,
                              hipStream_t stream) {
    const float* points        = (const float*)d_in[0];
    const float* features      = (const float*)d_in[1];
    const float* output_points = (const float*)d_in[2];
    const int*   nbr_idx       = (const int*)d_in[3];
    const int*   seg_ids       = (const int*)d_in[4];
    const float* k_points      = (const float*)d_in[5];
    const float* k_values      = (const float*)d_in[6];
    float* out = (float*)d_out;

    // ws layout (16B-aligned slabs)
    const size_t feat_bytes = (size_t)NPTS * FIN * sizeof(_Float16);          // 2.56 MB
    const size_t pts4_bytes = (size_t)NPTS * sizeof(float4);                  // 0.64 MB
    const size_t rs_bytes   = ((size_t)(MOUT + 1) * sizeof(int) + 15) & ~15ul;// 160 KB
    const size_t agg_bytes  = (size_t)MOUT * KFDIM * sizeof(unsigned short);  // 38.4 MB
    const size_t full_bytes = feat_bytes + pts4_bytes + rs_bytes + agg_bytes; // ~41.8 MB

    if (ws_size >= full_bytes) {
        char* p = (char*)d_ws;
        _Float16* feat_h      = (_Float16*)p;            p += feat_bytes;
        float4*   points4     = (float4*)p;              p += pts4_bytes;
        int*      row_start   = (int*)p;                 p += rs_bytes;
        unsigned short* agg_g = (unsigned short*)p;

        feat_to_f16<<<NPTS * FIN / 1024, 256, 0, stream>>>(features, feat_h);
        pts_to_f4<<<(NPTS + 255) / 256, 256, 0, stream>>>(points, points4);
        build_row_starts<<<(EDG + 255) / 256, 256, 0, stream>>>(seg_ids, row_start);
        kpconv_agg_mfma16<<<MOUT / 4, 256, 0, stream>>>(
            points4, feat_h, output_points, nbr_idx, row_start, k_points, agg_g);
        kpconv_gemm<<<MOUT / 32, 256, 0, stream>>>(agg_g, k_values, out);
    } else {
        unsigned short* agg_g = (unsigned short*)d_ws;   // needs 38.4 MB
        kpconv_agg_mfma<<<MOUT / 4, 256, 0, stream>>>(
            points, features, output_points, nbr_idx, seg_ids, k_points, agg_g);
        kpconv_gemm<<<MOUT / 32, 256, 0, stream>>>(agg_g, k_values, out);
    }
}